// Round 3
// baseline (409854.639 us; speedup 1.0000x reference)
//
#include <hip/hip_runtime.h>
#include <hip/hip_bf16.h>
#include <stdint.h>

#define SEQ     8192
#define DIM     2048
#define HID     1024
#define NLAYER  5
#define NWG     256
#define CPW     8      // output columns per workgroup

typedef unsigned long long u64;

// ---- workspace layout (bytes) ----
//   0     : Hbuf[1024]  (u64 pairs {f32 val, u32 tag}) -- hidden state, tag = step
//   8192  : bufA[2048]  (u64 pairs) -- layer act ping  (layers 0,2 write)
//   24576 : bufB[2048]  (u64 pairs) -- layer act pong  (layers 1,3 write)
//   total 40960, memset to 0 per call: val=0.0f, tag=0 == "H ready for t=0"

__device__ __forceinline__ uint16_t f2bf(float f) {
  union { float f; uint32_t u; } v; v.f = f;
  uint32_t r = v.u + 0x7FFFu + ((v.u >> 16) & 1u);   // round-to-nearest-even
  return (uint16_t)(r >> 16);
}
__device__ __forceinline__ float bf2f(uint16_t u) {
  union { uint32_t u; float f; } v; v.u = ((uint32_t)u) << 16; return v.f;
}

// 8B agent-scope relaxed atomics: single global_load/store_dwordx2 sc0 sc1 —
// coherent across XCDs (bypass stale L2), un-torn, no fences needed: the tag
// and the value travel in the same memory transaction.
__device__ __forceinline__ u64 cload64(const u64* p) {
  return __hip_atomic_load(const_cast<u64*>(p), __ATOMIC_RELAXED,
                           __HIP_MEMORY_SCOPE_AGENT);
}
__device__ __forceinline__ void cstore64(u64* p, u64 v) {
  __hip_atomic_store(p, v, __ATOMIC_RELAXED, __HIP_MEMORY_SCOPE_AGENT);
}
__device__ __forceinline__ u64 pack(float v, uint32_t tag) {
  union { float f; uint32_t u; } c; c.f = v;
  return ((u64)tag << 32) | (u64)c.u;
}
__device__ __forceinline__ float pval(u64 p) {
  union { uint32_t u; float f; } c; c.u = (uint32_t)p; return c.f;
}

// Poll N chunks of 4 consecutive pairs (col = j*256 + lane*4 + m) until every
// tag equals `tag`. Values land in pv[] registers, ready for immediate use.
template <int N>
__device__ __forceinline__ void poll_pairs(const u64* __restrict__ base,
                                           int lane, uint32_t tag, u64* pv) {
  for (;;) {
    #pragma unroll
    for (int j = 0; j < N; ++j) {
      #pragma unroll
      for (int m = 0; m < 4; ++m)
        pv[j * 4 + m] = cload64(base + j * 256 + lane * 4 + m);
    }
    bool ok = true;
    #pragma unroll
    for (int i = 0; i < 4 * N; ++i)
      ok &= ((uint32_t)(pv[i] >> 32) == tag);
    if (__all(ok)) return;
    __builtin_amdgcn_s_sleep(1);
  }
}

__global__ void __launch_bounds__(256, 1)
rnn_persist(const float* __restrict__ x, const float* __restrict__ W0,
            const float* __restrict__ b0, const float* __restrict__ Wmid,
            const float* __restrict__ bmid, const float* __restrict__ Wf,
            const float* __restrict__ bfv, float* __restrict__ out,
            u64* __restrict__ Hbuf, u64* __restrict__ bufA,
            u64* __restrict__ bufB)
{
  // 5 layers x 8 cols x 2048 k of bf16 = 163840 B = full 160 KiB LDS
  __shared__ uint16_t wlds[NLAYER * CPW * DIM];

  const int tid  = threadIdx.x;
  const int wg   = blockIdx.x;
  const int wave = tid >> 6;
  const int lane = tid & 63;

  // ---- stage this WG's weight slice (bf16) into LDS, once per call ----
  for (int i = tid; i < NLAYER * CPW * DIM; i += 256) {
    const int l = i >> 14;           // / (CPW*DIM)
    const int r = i & 16383;
    const int k = r >> 3;            // 0..2047
    const int c = r & 7;             // 0..7
    const float* Ws = (l == 0) ? W0
                    : (l <= 3 ? (Wmid + (size_t)(l - 1) * DIM * DIM) : Wf);
    wlds[(l * CPW + c) * DIM + k] = f2bf(Ws[(size_t)k * DIM + (wg * CPW + c)]);
  }
  __syncthreads();

  // each wave owns 2 adjacent output columns
  const int cidx0 = wave * 2;
  const int col0  = wg * CPW + cidx0;
  const int col1  = col0 + 1;

  float bias0[NLAYER], bias1[NLAYER];
  bias0[0] = b0[col0];              bias1[0] = b0[col1];
  bias0[1] = bmid[0 * DIM + col0];  bias1[1] = bmid[0 * DIM + col1];
  bias0[2] = bmid[1 * DIM + col0];  bias1[2] = bmid[1 * DIM + col1];
  bias0[3] = bmid[2 * DIM + col0];  bias1[3] = bmid[2 * DIM + col1];
  bias0[4] = bfv[col0];             bias1[4] = bfv[col1];

  for (int t = 0; t < SEQ; ++t) {
    const float* __restrict__ xrow = x + (size_t)t * HID;

    #pragma unroll
    for (int l = 0; l < NLAYER; ++l) {
      const uint16_t* w0p = wlds + ((l * CPW + cidx0) * DIM);
      const uint16_t* w1p = w0p + DIM;
      float acc0 = 0.f, acc1 = 0.f;

      if (l == 0) {
        // x half (k<1024): plain cached loads, computed while H is in flight
        #pragma unroll
        for (int j = 0; j < 4; ++j) {
          const int kb = j * 256 + lane * 4;
          const float4  a  = *(const float4*)(xrow + kb);
          const ushort4 wa = *(const ushort4*)(w0p + kb);
          const ushort4 wb = *(const ushort4*)(w1p + kb);
          acc0 = fmaf(a.x, bf2f(wa.x), acc0); acc1 = fmaf(a.x, bf2f(wb.x), acc1);
          acc0 = fmaf(a.y, bf2f(wa.y), acc0); acc1 = fmaf(a.y, bf2f(wb.y), acc1);
          acc0 = fmaf(a.z, bf2f(wa.z), acc0); acc1 = fmaf(a.z, bf2f(wb.z), acc1);
          acc0 = fmaf(a.w, bf2f(wa.w), acc0); acc1 = fmaf(a.w, bf2f(wb.w), acc1);
        }
        // H half (k>=1024): tagged pairs, tag == t
        u64 pv[16];
        poll_pairs<4>(Hbuf, lane, (uint32_t)t, pv);
        #pragma unroll
        for (int j = 0; j < 4; ++j) {
          const int kb = (j + 4) * 256 + lane * 4;
          const ushort4 wa = *(const ushort4*)(w0p + kb);
          const ushort4 wb = *(const ushort4*)(w1p + kb);
          #pragma unroll
          for (int m = 0; m < 4; ++m) {
            const float a = pval(pv[j * 4 + m]);        // hidden: no relu
            acc0 = fmaf(a, bf2f((&wa.x)[m]), acc0);
            acc1 = fmaf(a, bf2f((&wb.x)[m]), acc1);
          }
        }
      } else {
        const u64* __restrict__ src = (l & 1) ? bufA : bufB;
        u64 pv[32];
        poll_pairs<8>(src, lane, (uint32_t)(t * 4 + l), pv);
        #pragma unroll
        for (int j = 0; j < 8; ++j) {
          const int kb = j * 256 + lane * 4;
          const ushort4 wa = *(const ushort4*)(w0p + kb);
          const ushort4 wb = *(const ushort4*)(w1p + kb);
          #pragma unroll
          for (int m = 0; m < 4; ++m) {
            const float a = fmaxf(pval(pv[j * 4 + m]), 0.f);   // relu
            acc0 = fmaf(a, bf2f((&wa.x)[m]), acc0);
            acc1 = fmaf(a, bf2f((&wb.x)[m]), acc1);
          }
        }
      }

      // ---- 64-lane tree reduction ----
      #pragma unroll
      for (int off = 32; off > 0; off >>= 1) {
        acc0 += __shfl_xor(acc0, off, 64);
        acc1 += __shfl_xor(acc1, off, 64);
      }

      // ---- publish: value+tag in one 8B atomic store, fire and continue ----
      if (lane == 0) {
        const float v0 = acc0 + bias0[l];
        const float v1 = acc1 + bias1[l];
        if (l < 4) {
          u64* __restrict__ dst = (l & 1) ? bufB : bufA;
          const uint32_t tw = (uint32_t)(t * 4 + l + 1);
          cstore64(dst + col0, pack(v0, tw));
          cstore64(dst + col1, pack(v1, tw));
        } else if (col0 < HID) {
          if (t < SEQ - 1) {
            cstore64(Hbuf + col0, pack(v0, (uint32_t)(t + 1)));
            cstore64(Hbuf + col1, pack(v1, (uint32_t)(t + 1)));
          } else {
            float2 o; o.x = v0; o.y = v1;
            *(float2*)(out + col0) = o;                  // final hidden
          }
        } else {
          float2 o; o.x = v0; o.y = v1;
          *(float2*)(out + HID + (size_t)t * HID + (col0 - HID)) = o;  // outputs[t]
        }
      }
    }
  }
}

extern "C" void kernel_launch(void* const* d_in, const int* in_sizes, int n_in,
                              void* d_out, int out_size, void* d_ws, size_t ws_size,
                              hipStream_t stream) {
  (void)in_sizes; (void)n_in; (void)out_size; (void)ws_size;
  const float* x    = (const float*)d_in[0];
  const float* W0   = (const float*)d_in[1];
  const float* b0   = (const float*)d_in[2];
  const float* Wmid = (const float*)d_in[3];
  const float* bmid = (const float*)d_in[4];
  const float* Wf   = (const float*)d_in[5];
  const float* bfv  = (const float*)d_in[6];
  float* out = (float*)d_out;

  uint8_t* ws = (uint8_t*)d_ws;
  u64* Hbuf = (u64*)(ws + 0);
  u64* bufA = (u64*)(ws + 8192);
  u64* bufB = (u64*)(ws + 24576);

  // reset tags + hidden state every call: tag 0 == "H ready for t=0", H = 0.0f
  hipMemsetAsync(d_ws, 0, 40960, stream);

  rnn_persist<<<dim3(NWG), dim3(256), 0, stream>>>(
      x, W0, b0, Wmid, bmid, Wf, bfv, out, Hbuf, bufA, bufB);
}

// Round 4
// 218907.178 us; speedup vs baseline: 1.8723x; 1.8723x over previous
//
#include <hip/hip_runtime.h>
#include <hip/hip_bf16.h>
#include <stdint.h>

#define SEQ     8192
#define DIM     2048
#define HID     1024
#define NWG     256
#define CPW     8      // output columns per workgroup

typedef unsigned long long u64;

// ---- workspace layout (bytes) ----
//   0     : flags[256] (u32)   -- per-WG phase flag (5t+l+1 after layer l of step t)
//   4096  : H[1024]    (f32)   -- hidden state (written as u64 pairs)
//   8192  : actA[2048] (f32)   -- layer act ping (layers 0,2 write; 1,3 read)
//   16384 : actB[2048] (f32)   -- layer act pong (layers 1,3 write; 2,4 read)
//   memset first 24576 B per call: flags=0, H=0 ("ready for t=0")

__device__ __forceinline__ uint16_t f2bf(float f) {
  union { float f; uint32_t u; } v; v.f = f;
  uint32_t r = v.u + 0x7FFFu + ((v.u >> 16) & 1u);   // round-to-nearest-even
  return (uint16_t)(r >> 16);
}
__device__ __forceinline__ float bf2f(uint16_t u) {
  union { uint32_t u; float f; } v; v.u = ((uint32_t)u) << 16; return v.f;
}

// agent-scope relaxed atomics -> global_load/store ... sc0 sc1: coherent at L3,
// bypass (and never allocate into) the non-coherent L1/L2. No fences needed.
__device__ __forceinline__ uint32_t cload32(const uint32_t* p) {
  return __hip_atomic_load(const_cast<uint32_t*>(p), __ATOMIC_RELAXED,
                           __HIP_MEMORY_SCOPE_AGENT);
}
__device__ __forceinline__ void cstore32(uint32_t* p, uint32_t v) {
  __hip_atomic_store(p, v, __ATOMIC_RELAXED, __HIP_MEMORY_SCOPE_AGENT);
}
__device__ __forceinline__ u64 cload64(const u64* p) {
  return __hip_atomic_load(const_cast<u64*>(p), __ATOMIC_RELAXED,
                           __HIP_MEMORY_SCOPE_AGENT);
}
__device__ __forceinline__ void cstore64(u64* p, u64 v) {
  __hip_atomic_store(p, v, __ATOMIC_RELAXED, __HIP_MEMORY_SCOPE_AGENT);
}
__device__ __forceinline__ u64 packf2(float a, float b) {
  union { float2 f; u64 u; } c; c.f.x = a; c.f.y = b; return c.u;
}
__device__ __forceinline__ float2 unpackf2(u64 u) {
  union { u64 u; float2 f; } c; c.u = u; return c.f;
}

__global__ void __launch_bounds__(256, 1)
rnn_persist(const float* __restrict__ x, const float* __restrict__ W0,
            const float* __restrict__ b0, const float* __restrict__ Wmid,
            const float* __restrict__ bmid, const float* __restrict__ Wf,
            const float* __restrict__ bfv, float* __restrict__ out,
            uint32_t* __restrict__ flags, float* __restrict__ Hbuf,
            float* __restrict__ actA, float* __restrict__ actB)
{
  __shared__ uint16_t wlds[4 * CPW * DIM];   // layers 0-3 weights, 128 KiB
  __shared__ float    sAct[DIM];             // staged activation vector, 8 KiB

  const int tid  = threadIdx.x;
  const int wg   = blockIdx.x;
  const int wave = tid >> 6;
  const int lane = tid & 63;

  // each wave owns 2 adjacent output columns of every layer
  const int cidx0 = wave * 2;
  const int col0  = wg * CPW + cidx0;
  const int col1  = col0 + 1;

  // ---- stage layers 0-3 weight slice (bf16) into LDS, once ----
  for (int i = tid; i < 4 * CPW * DIM; i += 256) {
    const int l = i >> 14;           // / (CPW*DIM)
    const int r = i & 16383;
    const int k = r >> 3;            // 0..2047
    const int c = r & 7;             // 0..7
    const float* Ws = (l == 0) ? W0 : (Wmid + (size_t)(l - 1) * DIM * DIM);
    wlds[(l * CPW + c) * DIM + k] = f2bf(Ws[(size_t)k * DIM + (wg * CPW + c)]);
  }
  // ---- layer-4 weights into registers: 2 cols x 32 k-vals/lane = 32 VGPR ----
  ushort4 wf0[8], wf1[8];
  #pragma unroll
  for (int j = 0; j < 8; ++j) {
    const int k = j * 256 + lane * 4;
    wf0[j].x = f2bf(Wf[(size_t)(k + 0) * DIM + col0]);
    wf0[j].y = f2bf(Wf[(size_t)(k + 1) * DIM + col0]);
    wf0[j].z = f2bf(Wf[(size_t)(k + 2) * DIM + col0]);
    wf0[j].w = f2bf(Wf[(size_t)(k + 3) * DIM + col0]);
    wf1[j].x = f2bf(Wf[(size_t)(k + 0) * DIM + col1]);
    wf1[j].y = f2bf(Wf[(size_t)(k + 1) * DIM + col1]);
    wf1[j].z = f2bf(Wf[(size_t)(k + 2) * DIM + col1]);
    wf1[j].w = f2bf(Wf[(size_t)(k + 3) * DIM + col1]);
  }
  __syncthreads();

  float bias0[5], bias1[5];
  bias0[0] = b0[col0];              bias1[0] = b0[col1];
  bias0[1] = bmid[0 * DIM + col0];  bias1[1] = bmid[0 * DIM + col1];
  bias0[2] = bmid[1 * DIM + col0];  bias1[2] = bmid[1 * DIM + col1];
  bias0[3] = bmid[2 * DIM + col0];  bias1[3] = bmid[2 * DIM + col1];
  bias0[4] = bfv[col0];             bias1[4] = bfv[col1];

  const bool hWG = (wg < 128);   // layer-4 columns of this WG are H (else outputs)

  for (int t = 0; t < SEQ; ++t) {
    const float* __restrict__ xrow = x + (size_t)t * HID;

    #pragma unroll
    for (int l = 0; l < 5; ++l) {
      // ================= acquire + stage this wave's quarter =================
      if (l == 0) {
        if (wave < 2) {
          // x half: plain cached loads, no dependency (overlaps H wait below)
          const int f0 = wave * 512 + lane * 8;
          const float4 a0 = *(const float4*)(xrow + f0);
          const float4 a1 = *(const float4*)(xrow + f0 + 4);
          *(float4*)&sAct[f0]     = a0;
          *(float4*)&sAct[f0 + 4] = a1;
        } else {
          // H half: poll the 64 H-producer WGs of this quarter, then load
          const int hq = wave - 2;                       // 0 or 1
          const uint32_t tgt = 5u * (uint32_t)t;         // flag after L4(t-1)
          const uint32_t* fp = flags + hq * 64 + lane;
          for (;;) {
            if (__all((int)(cload32(fp) >= tgt))) break;
            __builtin_amdgcn_s_sleep(1);
          }
          asm volatile("" ::: "memory");
          const u64* hp = (const u64*)Hbuf + hq * 256 + lane * 4;
          const u64 p0 = cload64(hp + 0), p1 = cload64(hp + 1);
          const u64 p2 = cload64(hp + 2), p3 = cload64(hp + 3);
          const int f0 = 1024 + hq * 512 + lane * 8;
          *(float2*)&sAct[f0 + 0] = unpackf2(p0);        // hidden: no relu
          *(float2*)&sAct[f0 + 2] = unpackf2(p1);
          *(float2*)&sAct[f0 + 4] = unpackf2(p2);
          *(float2*)&sAct[f0 + 6] = unpackf2(p3);
        }
      } else {
        const u64* __restrict__ src = (const u64*)((l & 1) ? actA : actB);
        const uint32_t tgt = 5u * (uint32_t)t + (uint32_t)l;
        const uint32_t* fp = flags + wave * 64 + lane;
        for (;;) {
          if (__all((int)(cload32(fp) >= tgt))) break;
          __builtin_amdgcn_s_sleep(1);
        }
        asm volatile("" ::: "memory");
        const u64* sp = src + wave * 256 + lane * 4;
        const u64 p0 = cload64(sp + 0), p1 = cload64(sp + 1);
        const u64 p2 = cload64(sp + 2), p3 = cload64(sp + 3);
        const int f0 = wave * 512 + lane * 8;
        float2 v0 = unpackf2(p0), v1 = unpackf2(p1);
        float2 v2 = unpackf2(p2), v3 = unpackf2(p3);
        v0.x = fmaxf(v0.x, 0.f); v0.y = fmaxf(v0.y, 0.f);   // relu at stage time
        v1.x = fmaxf(v1.x, 0.f); v1.y = fmaxf(v1.y, 0.f);
        v2.x = fmaxf(v2.x, 0.f); v2.y = fmaxf(v2.y, 0.f);
        v3.x = fmaxf(v3.x, 0.f); v3.y = fmaxf(v3.y, 0.f);
        *(float2*)&sAct[f0 + 0] = v0;
        *(float2*)&sAct[f0 + 2] = v1;
        *(float2*)&sAct[f0 + 4] = v2;
        *(float2*)&sAct[f0 + 6] = v3;
      }
      __syncthreads();   // staging complete -> full vector visible to all waves

      // ========================== dot products ==========================
      float acc0 = 0.f, acc1 = 0.f;
      if (l < 4) {
        const uint16_t* w0p = wlds + ((l * CPW + cidx0) * DIM);
        const uint16_t* w1p = w0p + DIM;
        #pragma unroll
        for (int j = 0; j < 8; ++j) {
          const int kb = j * 256 + lane * 4;
          const float4  a  = *(const float4*)&sAct[kb];
          const ushort4 wa = *(const ushort4*)(w0p + kb);
          const ushort4 wb = *(const ushort4*)(w1p + kb);
          acc0 = fmaf(a.x, bf2f(wa.x), acc0); acc1 = fmaf(a.x, bf2f(wb.x), acc1);
          acc0 = fmaf(a.y, bf2f(wa.y), acc0); acc1 = fmaf(a.y, bf2f(wb.y), acc1);
          acc0 = fmaf(a.z, bf2f(wa.z), acc0); acc1 = fmaf(a.z, bf2f(wb.z), acc1);
          acc0 = fmaf(a.w, bf2f(wa.w), acc0); acc1 = fmaf(a.w, bf2f(wb.w), acc1);
        }
      } else {
        #pragma unroll
        for (int j = 0; j < 8; ++j) {
          const int kb = j * 256 + lane * 4;
          const float4  a  = *(const float4*)&sAct[kb];
          const ushort4 wa = wf0[j];
          const ushort4 wb = wf1[j];
          acc0 = fmaf(a.x, bf2f(wa.x), acc0); acc1 = fmaf(a.x, bf2f(wb.x), acc1);
          acc0 = fmaf(a.y, bf2f(wa.y), acc0); acc1 = fmaf(a.y, bf2f(wb.y), acc1);
          acc0 = fmaf(a.z, bf2f(wa.z), acc0); acc1 = fmaf(a.z, bf2f(wb.z), acc1);
          acc0 = fmaf(a.w, bf2f(wa.w), acc0); acc1 = fmaf(a.w, bf2f(wb.w), acc1);
        }
      }
      #pragma unroll
      for (int off = 32; off > 0; off >>= 1) {
        acc0 += __shfl_xor(acc0, off, 64);
        acc1 += __shfl_xor(acc1, off, 64);
      }

      // ========================== publish ==========================
      const bool finalStep = (t == SEQ - 1);
      // does this WG publish coherent data + flag this phase?
      const bool producer = (l < 4) || (hWG && !finalStep);

      if (lane == 0) {
        const float v0 = acc0 + bias0[l];
        const float v1 = acc1 + bias1[l];
        if (l < 4) {
          u64* dst = (u64*)((l & 1) ? actB : actA);
          cstore64(dst + (col0 >> 1), packf2(v0, v1));
        } else if (hWG) {
          if (!finalStep) {
            cstore64((u64*)Hbuf + (col0 >> 1), packf2(v0, v1));
          } else {
            float2 o; o.x = v0; o.y = v1;
            *(float2*)(out + col0) = o;                          // final hidden
          }
        } else {
          float2 o; o.x = v0; o.y = v1;
          *(float2*)(out + HID + (size_t)t * HID + (col0 - HID)) = o;  // outputs[t]
        }
      }
      if (producer)
        asm volatile("s_waitcnt vmcnt(0)" ::: "memory");  // data at L3 pre-flag
      __syncthreads();                                    // all 4 waves done
      if (tid == 0 && producer)
        cstore32(flags + wg, 5u * (uint32_t)t + (uint32_t)l + 1u);
    }
  }
}

extern "C" void kernel_launch(void* const* d_in, const int* in_sizes, int n_in,
                              void* d_out, int out_size, void* d_ws, size_t ws_size,
                              hipStream_t stream) {
  (void)in_sizes; (void)n_in; (void)out_size; (void)ws_size;
  const float* x    = (const float*)d_in[0];
  const float* W0   = (const float*)d_in[1];
  const float* b0   = (const float*)d_in[2];
  const float* Wmid = (const float*)d_in[3];
  const float* bmid = (const float*)d_in[4];
  const float* Wf   = (const float*)d_in[5];
  const float* bfv  = (const float*)d_in[6];
  float* out = (float*)d_out;

  uint8_t* ws = (uint8_t*)d_ws;
  uint32_t* flags = (uint32_t*)(ws + 0);
  float*    Hbuf  = (float*)(ws + 4096);
  float*    actA  = (float*)(ws + 8192);
  float*    actB  = (float*)(ws + 16384);

  // reset flags + hidden state every call (graph-replay safe)
  hipMemsetAsync(d_ws, 0, 24576, stream);

  rnn_persist<<<dim3(NWG), dim3(256), 0, stream>>>(
      x, W0, b0, Wmid, bmid, Wf, bfv, out, flags, Hbuf, actA, actB);
}